// Round 1
// baseline (68.804 us; speedup 1.0000x reference)
//
#include <hip/hip_runtime.h>
#include <math.h>

#define SRC_H 480
#define SRC_W 640
#define RES_H 384
#define RES_W 512
#define NT 16
#define NPIX (RES_H * RES_W)        /* 196608 */
#define PLANE (SRC_H * SRC_W)       /* 307200 */
#define NCHUNK 32
#define CHUNK_SZ (PLANE / NCHUNK)   /* 9600 */

/* output layout (floats, concatenated in return order) */
#define O_SPARSE 0
#define N_SPARSE (NT * 96 * 128 * 2)            /* 393216 */
#define O_XY (O_SPARSE + N_SPARSE)
#define N_XY (NT * NPIX * 2)
#define O_Z (O_XY + N_XY)
#define N_Z (NT * NPIX)
#define O_VIS (O_Z + N_Z)
#define O_TRAJ (O_VIS + N_Z)

/* ws layout: double part[48*32] (12288 B), then floats:
   ay[480] @ float ofs 3072, ax[640] @ 3552, disp[32] @ 4192, fm[16] @ 4224 */

__global__ void weights_kernel(float* __restrict__ ay, float* __restrict__ ax) {
    int i = blockIdx.x * blockDim.x + threadIdx.x;
    if (i < SRC_H) {
        const float s = 479.0f / 383.0f;
        float acc = 0.f;
        int lo = (int)floorf((float)(i - 1) / s) - 2; if (lo < 0) lo = 0;
        int hi = (int)ceilf((float)(i + 1) / s) + 2; if (hi > RES_H - 1) hi = RES_H - 1;
        for (int oy = lo; oy <= hi; ++oy) {
            float ys = (float)oy * s;
            int y0 = (int)floorf(ys);
            float wy = ys - (float)y0;
            int y1 = min(y0 + 1, SRC_H - 1);
            if (y0 == i) acc += (1.f - wy);
            if (y1 == i) acc += wy;
        }
        ay[i] = acc * (1.0f / RES_H);
    } else if (i >= 512 && i < 512 + SRC_W) {
        int xs = i - 512;
        const float s = 639.0f / 511.0f;
        float acc = 0.f;
        int lo = (int)floorf((float)(xs - 1) / s) - 2; if (lo < 0) lo = 0;
        int hi = (int)ceilf((float)(xs + 1) / s) + 2; if (hi > RES_W - 1) hi = RES_W - 1;
        for (int ox = lo; ox <= hi; ++ox) {
            float xv = (float)ox * s;
            int x0 = (int)floorf(xv);
            float wx = xv - (float)x0;
            int x1 = min(x0 + 1, SRC_W - 1);
            if (x0 == xs) acc += (1.f - wx);
            if (x1 == xs) acc += wx;
        }
        ax[xs] = acc * (1.0f / RES_W);
    }
}

__global__ __launch_bounds__(256) void feat_partial_kernel(
        const float* __restrict__ video, const float* __restrict__ ay,
        const float* __restrict__ ax, double* __restrict__ part) {
    int chunk = blockIdx.x;   /* 0..31 */
    int plane = blockIdx.y;   /* 0..47  (= t*3 + c) */
    const float* v = video + (size_t)plane * PLANE + (size_t)chunk * CHUNK_SZ;
    int base = chunk * CHUNK_SZ;
    double s = 0.0;
    for (int i = threadIdx.x; i < CHUNK_SZ; i += 256) {
        int p = base + i;
        int y = p / SRC_W;
        int x = p - y * SRC_W;
        s += (double)(ay[y] * ax[x]) * (double)v[i];
    }
    __shared__ double sh[256];
    sh[threadIdx.x] = s;
    __syncthreads();
    for (int off = 128; off > 0; off >>= 1) {
        if (threadIdx.x < off) sh[threadIdx.x] += sh[threadIdx.x + off];
        __syncthreads();
    }
    if (threadIdx.x == 0) part[plane * NCHUNK + chunk] = sh[0];
}

__global__ void finalize_kernel(const double* __restrict__ part,
                                float* __restrict__ disp, float* __restrict__ fm) {
    __shared__ float feats[48];
    int tid = threadIdx.x;
    if (tid < 48) {
        double s = 0.0;
        for (int k = 0; k < NCHUNK; ++k) s += part[tid * NCHUNK + k];
        feats[tid] = (float)s;
    }
    __syncthreads();
    if (tid < NT) {
        float f0 = feats[tid * 3 + 0];
        float f1 = feats[tid * 3 + 1];
        float f2 = feats[tid * 3 + 2];
        disp[2 * tid + 0] = tanhf(f0) * 2.0f;
        disp[2 * tid + 1] = tanhf(f1) * 2.0f;
        fm[tid] = ((f0 + f1) + f2) / 3.0f;
    }
}

__global__ __launch_bounds__(256) void main_kernel(
        const float* __restrict__ video, const float* __restrict__ depth,
        const float* __restrict__ disp, const float* __restrict__ fm,
        float* __restrict__ out) {
    int gid = blockIdx.x * 256 + threadIdx.x;
    if (gid >= NT * NPIX) return;
    int t = gid / NPIX;
    int rem = gid - t * NPIX;
    int y = rem >> 9;
    int x = rem & 511;

    float qx = (float)x, qy = (float)y;
    bool covered = (x < 510);
    float xtrk = 0.f, ytrk = 0.f, dval = 0.f, visv = 0.f;

    if (covered) {
        float dx = disp[2 * t + 0];
        float dy = disp[2 * t + 1];
        float tf = (float)t;
        float txv = qx + tf * dx;
        txv = fminf(fmaxf(txv, 0.f), 511.f);
        float tyv = qy + tf * dy;
        tyv = fminf(fmaxf(tyv, 0.f), 383.f);

        int x0 = (int)floorf(txv); int x1 = min(x0 + 1, RES_W - 1); float wx = txv - (float)x0;
        int y0 = (int)floorf(tyv); int y1 = min(y0 + 1, RES_H - 1); float wy = tyv - (float)y0;
        /* nearest-resized depth: dep(y,x) = depth[t, y+(y>>2), x+(x>>2)] */
        const float* dep = depth + (size_t)t * PLANE;
        int sx0 = x0 + (x0 >> 2), sx1 = x1 + (x1 >> 2);
        int sy0 = y0 + (y0 >> 2), sy1 = y1 + (y1 >> 2);
        float d00 = dep[sy0 * SRC_W + sx0];
        float d01 = dep[sy0 * SRC_W + sx1];
        float d10 = dep[sy1 * SRC_W + sx0];
        float d11 = dep[sy1 * SRC_W + sx1];
        dval = d00 * ((1.f - wx) * (1.f - wy)) + d01 * (wx * (1.f - wy))
             + d10 * ((1.f - wx) * wy) + d11 * (wx * wy);

        float z = 3.0f * sinf(0.05f * (qx + qy)) + fm[t];
        float sg = 1.f / (1.f + expf(-z));
        visv = (sg > 0.8f) ? 1.f : 0.f;

        xtrk = txv * (639.f / 511.f);
        ytrk = tyv * (479.f / 383.f);
    }

    /* trajs_3d pieces */
    float X = (xtrk - 320.f) / 640.f;
    float Y = (ytrk - 240.f) / 640.f;
    /* grid-sample coords, stepwise like the reference */
    float a1 = xtrk / 640.f; float b1 = 2.f * (a1 - 0.5f); float c1 = b1 + 1.f;
    float px = (c1 * 0.5f) * 639.f;
    float a2 = ytrk / 480.f; float b2 = 2.f * (a2 - 0.5f); float c2 = b2 + 1.f;
    float py = (c2 * 0.5f) * 479.f;
    px = fminf(fmaxf(px, 0.f), 639.f);
    py = fminf(fmaxf(py, 0.f), 479.f);
    int cx0 = (int)floorf(px); int cx1 = min(cx0 + 1, SRC_W - 1); float cwx = px - (float)cx0;
    int cy0 = (int)floorf(py); int cy1 = min(cy0 + 1, SRC_H - 1); float cwy = py - (float)cy0;

    const float* vt = video + (size_t)t * 3 * PLANE;
    float col[3];
#pragma unroll
    for (int c = 0; c < 3; ++c) {
        const float* vc = vt + (size_t)c * PLANE;
        float v00 = vc[cy0 * SRC_W + cx0];
        float v01 = vc[cy0 * SRC_W + cx1];
        float v10 = vc[cy1 * SRC_W + cx0];
        float v11 = vc[cy1 * SRC_W + cx1];
        col[c] = v00 * ((1.f - cwx) * (1.f - cwy)) + v01 * (cwx * (1.f - cwy))
               + v10 * ((1.f - cwx) * cwy) + v11 * (cwx * cwy);
    }

    size_t tb = (size_t)t * NPIX + (size_t)rem;
    out[O_XY + tb * 2 + 0] = xtrk;
    out[O_XY + tb * 2 + 1] = ytrk;
    out[O_Z + tb] = dval;
    out[O_VIS + tb] = visv;
    float* tr = out + O_TRAJ + tb * 7;
    tr[0] = X; tr[1] = Y; tr[2] = dval;
    tr[3] = col[0]; tr[4] = col[1]; tr[5] = col[2];
    tr[6] = visv;

    if (((x | y) & 3) == 0) {
        int ns = (y >> 2) * 128 + (x >> 2);
        size_t sb = (size_t)t * (96 * 128) + (size_t)ns;
        out[O_SPARSE + sb * 2 + 0] = xtrk;
        out[O_SPARSE + sb * 2 + 1] = ytrk;
    }
}

extern "C" void kernel_launch(void* const* d_in, const int* in_sizes, int n_in,
                              void* d_out, int out_size, void* d_ws, size_t ws_size,
                              hipStream_t stream) {
    const float* video = (const float*)d_in[0];
    const float* depth = (const float*)d_in[1];
    float* out = (float*)d_out;

    double* part = (double*)d_ws;            /* 48*32 doubles = 12288 B */
    float* wsf = (float*)d_ws;
    float* ay = wsf + 3072;                  /* 480 */
    float* ax = wsf + 3552;                  /* 640 */
    float* disp = wsf + 4192;                /* 32 */
    float* fm = wsf + 4224;                  /* 16 */

    weights_kernel<<<5, 256, 0, stream>>>(ay, ax);
    feat_partial_kernel<<<dim3(NCHUNK, NT * 3), 256, 0, stream>>>(video, ay, ax, part);
    finalize_kernel<<<1, 64, 0, stream>>>(part, disp, fm);
    main_kernel<<<(NT * NPIX) / 256, 256, 0, stream>>>(video, depth, disp, fm, out);
}